// Round 5
// baseline (343.412 us; speedup 1.0000x reference)
//
#include <hip/hip_runtime.h>

// Problem constants (match reference)
#define NN      4096   // N and N_NEXT
#define NU      2048   // NUM_UNSTABLE
#define PROWS   8192   // P_ROWS

// d_ws layout (floats):
//   [0,     4096) : sV       — sV[m] = sum_k V_next[k] * W_next[m][k]  (ROW dot)
//   [4096,  6144) : pP       = pi_i @ P_i      (column outputs)
//   [6144,  8192) : pPhat    = pi_i @ P_hat_i  (column outputs)
//   [8192, 12288) : rank (int) — exclusive count of unstable neurons with index < n

// ---------------------------------------------------------------------------
// Kernel 1: zero the accumulator region + compute unstable ranks (block scan).
// One block, 1024 threads, 4 neurons/thread.
// ---------------------------------------------------------------------------
__global__ __launch_bounds__(1024)
void rank_and_zero(const float* __restrict__ L, const float* __restrict__ U,
                   float* __restrict__ ws) {
  const int tid = threadIdx.x;

  float4 z = make_float4(0.f, 0.f, 0.f, 0.f);
  reinterpret_cast<float4*>(ws)[tid * 2 + 0] = z;
  reinterpret_cast<float4*>(ws)[tid * 2 + 1] = z;

  int* rank = reinterpret_cast<int*>(ws + 8192);

  const int base = tid * 4;
  int m[4];
  int cnt = 0;
#pragma unroll
  for (int j = 0; j < 4; ++j) {
    const float l = L[base + j], u = U[base + j];
    m[j] = (l < 0.f && u > 0.f) ? 1 : 0;
    cnt += m[j];
  }

  const int lane = tid & 63;
  const int wave = tid >> 6;
  int scan = cnt;
#pragma unroll
  for (int off = 1; off < 64; off <<= 1) {
    int nb = __shfl_up(scan, off, 64);
    if (lane >= off) scan += nb;
  }

  __shared__ int wave_sums[16];
  if (lane == 63) wave_sums[wave] = scan;
  __syncthreads();

  if (wave == 0 && lane < 16) {
    int s = wave_sums[lane];
#pragma unroll
    for (int off = 1; off < 16; off <<= 1) {
      int nb = __shfl_up(s, off, 64);
      if (lane >= off) s += nb;
    }
    wave_sums[lane] = s;
  }
  __syncthreads();

  const int wave_off = (wave > 0) ? wave_sums[wave - 1] : 0;
  int exc = wave_off + scan - cnt;
#pragma unroll
  for (int j = 0; j < 4; ++j) {
    rank[base + j] = exc;
    exc += m[j];
  }
}

// ---------------------------------------------------------------------------
// Kernel 2: fused mat-vec, UNIFORM 64 KB work tiles for load balance.
//   bid [0,1024):    W row-dots. Block = 4 rows (64 KB), one wave per row,
//                    float4-coalesced, shfl_xor reduce, lane 0 stores.
//                    Rows with U<=0 skipped (sV never consumed).
//   bid [1024,2048): P  chunks: 8 rows x 2048 cols (64 KB), per-thread
//                    register accumulation over rows, 8 atomicAdds.
//   bid [2048,3072): P_hat chunks, same shape.
// ---------------------------------------------------------------------------
__global__ __launch_bounds__(256)
void fused_matvec(const float* __restrict__ V_next, const float* __restrict__ W,
                  const float* __restrict__ pi, const float* __restrict__ P,
                  const float* __restrict__ Phat, const float* __restrict__ U,
                  float* __restrict__ ws) {
  const int bid = blockIdx.x;
  const int tid = threadIdx.x;

  if (bid < 1024) {
    // ---- W row dot ----
    const int wave = tid >> 6;
    const int lane = tid & 63;
    const int row  = bid * 4 + wave;
    if (U[row] <= 0.f) return;  // stably deactivated: sV unused

    const float4* Wr = reinterpret_cast<const float4*>(W + (size_t)row * NN);
    const float4* V4 = reinterpret_cast<const float4*>(V_next);

    float acc = 0.f;
#pragma unroll
    for (int it = 0; it < 16; ++it) {
      const float4 w4 = Wr[it * 64 + lane];
      const float4 v4 = V4[it * 64 + lane];
      acc = fmaf(w4.x, v4.x, acc);
      acc = fmaf(w4.y, v4.y, acc);
      acc = fmaf(w4.z, v4.z, acc);
      acc = fmaf(w4.w, v4.w, acc);
    }
#pragma unroll
    for (int off = 32; off > 0; off >>= 1) acc += __shfl_xor(acc, off, 64);
    if (lane == 0) ws[row] = acc;
  } else {
    // ---- P / Phat column dots: 8 rows x 2048 cols per block ----
    const int b    = bid - 1024;
    const int seg  = b >> 10;          // 0 -> P, 1 -> Phat
    const int c    = b & 1023;         // chunk index
    const int row0 = c * 8;

    const float* mat = seg ? Phat : P;
    float* out = ws + (seg ? 6144 : 4096);

    const float* mp = mat + (size_t)row0 * NU + tid * 4;
    float4 a0 = make_float4(0.f, 0.f, 0.f, 0.f);
    float4 a1 = make_float4(0.f, 0.f, 0.f, 0.f);
#pragma unroll
    for (int r = 0; r < 8; ++r) {
      const float v  = pi[row0 + r];   // wave-uniform scalar load
      const float4 m0 = *reinterpret_cast<const float4*>(mp + (size_t)r * NU);
      const float4 m1 = *reinterpret_cast<const float4*>(mp + (size_t)r * NU + 1024);
      a0.x = fmaf(v, m0.x, a0.x);  a0.y = fmaf(v, m0.y, a0.y);
      a0.z = fmaf(v, m0.z, a0.z);  a0.w = fmaf(v, m0.w, a0.w);
      a1.x = fmaf(v, m1.x, a1.x);  a1.y = fmaf(v, m1.y, a1.y);
      a1.z = fmaf(v, m1.z, a1.z);  a1.w = fmaf(v, m1.w, a1.w);
    }
    const int col = tid * 4;
    atomicAdd(out + col + 0, a0.x);
    atomicAdd(out + col + 1, a0.y);
    atomicAdd(out + col + 2, a0.z);
    atomicAdd(out + col + 3, a0.w);
    atomicAdd(out + 1024 + col + 0, a1.x);
    atomicAdd(out + 1024 + col + 1, a1.y);
    atomicAdd(out + 1024 + col + 2, a1.z);
    atomicAdd(out + 1024 + col + 3, a1.w);
  }
}

// ---------------------------------------------------------------------------
// Kernel 3: epilogue — masks + unstable formula.
// Reference override order: stably_deact (-C) overrides stably_act (sV - C).
// ---------------------------------------------------------------------------
__global__ __launch_bounds__(256)
void epilogue(const float* __restrict__ ws, const float* __restrict__ C,
              const float* __restrict__ L, const float* __restrict__ U,
              const float* __restrict__ alpha, float* __restrict__ out) {
  const int n = blockIdx.x * 256 + threadIdx.x;
  if (n >= NN) return;
  const float l = L[n], u = U[n], c = C[n];
  const int* rank = reinterpret_cast<const int*>(ws + 8192);

  float res;
  if (u <= 0.f) {
    res = -c;                       // stably deactivated
  } else if (l >= 0.f) {
    res = ws[n] - c;                // stably activated: sV - C
  } else {
    const int uu = rank[n];
    const float vhat = ws[n] - ws[6144 + uu];
    const float pos = fmaxf(vhat, 0.f);
    const float neg = fmaxf(-vhat, 0.f);
    res = pos * u / (u - l) - c - alpha[uu] * neg - ws[4096 + uu];
  }
  out[n] = res;
}

extern "C" void kernel_launch(void* const* d_in, const int* in_sizes, int n_in,
                              void* d_out, int out_size, void* d_ws, size_t ws_size,
                              hipStream_t stream) {
  const float* V_next  = (const float*)d_in[0];
  const float* W_next  = (const float*)d_in[1];
  const float* C_i     = (const float*)d_in[2];
  const float* L_i     = (const float*)d_in[3];
  const float* U_i     = (const float*)d_in[4];
  const float* P_i     = (const float*)d_in[5];
  const float* P_hat_i = (const float*)d_in[6];
  const float* pi_i    = (const float*)d_in[7];
  const float* alpha_i = (const float*)d_in[8];
  float* out = (float*)d_out;
  float* ws  = (float*)d_ws;

  rank_and_zero<<<1, 1024, 0, stream>>>(L_i, U_i, ws);
  fused_matvec<<<3072, 256, 0, stream>>>(V_next, W_next, pi_i, P_i, P_hat_i, U_i, ws);
  epilogue<<<NN / 256, 256, 0, stream>>>(ws, C_i, L_i, U_i, alpha_i, out);
}

// Round 6
// 228.868 us; speedup vs baseline: 1.5005x; 1.5005x over previous
//
#include <hip/hip_runtime.h>

// Problem constants (match reference)
#define NN      4096   // N and N_NEXT
#define NU      2048   // NUM_UNSTABLE
#define PROWS   8192   // P_ROWS
#define NCHUNK  256    // row-chunks per P matrix (32 rows each)

// d_ws layout (floats):
//   [0,     4096)  : sV      — sV[m] = dot(V_next, W_next[m,:])
//   [4096,  8192)  : rank (int) — exclusive count of unstable with index < n
//   [8192,  10240) : pP      = pi @ P       (final)
//   [10240, 12288) : pPhat   = pi @ P_hat   (final)
//   [12288, 12288 + 2*NCHUNK*2048) : per-chunk partials  (4 MB)
#define WS_PARTIAL 12288
#define WS_NEEDED  ((WS_PARTIAL + 2 * NCHUNK * 2048) * sizeof(float))

// ---------------------------------------------------------------------------
// Stage 1: atomic-free partial mat-vec.
//   bid [0, 2*NCHUNK):        heavy: 32 rows x 2048 cols of P (seg 0) or
//                             P_hat (seg 1); writes 2048-float partial vector
//                             to its private slot. Scheduled FIRST (big tiles).
//   bid [2*NCHUNK, +1024):    light: 4 W-rows per block, one wave per row,
//                             float4 + shfl_xor reduce; skips U<=0 rows.
// ---------------------------------------------------------------------------
__global__ __launch_bounds__(256)
void stage1(const float* __restrict__ V_next, const float* __restrict__ W,
            const float* __restrict__ pi, const float* __restrict__ P,
            const float* __restrict__ Phat, const float* __restrict__ U,
            float* __restrict__ ws) {
  const int bid = blockIdx.x;
  const int tid = threadIdx.x;

  if (bid < 2 * NCHUNK) {
    // ---- heavy: P / Phat partial column sums ----
    const int seg  = bid >> 8;          // 0 -> P, 1 -> Phat
    const int c    = bid & (NCHUNK - 1);
    const int row0 = c * 32;
    const float* mat = seg ? Phat : P;

    const float* mp = mat + (size_t)row0 * NU + tid * 4;
    float4 a0 = make_float4(0.f, 0.f, 0.f, 0.f);
    float4 a1 = make_float4(0.f, 0.f, 0.f, 0.f);
#pragma unroll 8
    for (int r = 0; r < 32; ++r) {
      const float v  = pi[row0 + r];    // wave-uniform scalar load
      const float4 m0 = *reinterpret_cast<const float4*>(mp + (size_t)r * NU);
      const float4 m1 = *reinterpret_cast<const float4*>(mp + (size_t)r * NU + 1024);
      a0.x = fmaf(v, m0.x, a0.x);  a0.y = fmaf(v, m0.y, a0.y);
      a0.z = fmaf(v, m0.z, a0.z);  a0.w = fmaf(v, m0.w, a0.w);
      a1.x = fmaf(v, m1.x, a1.x);  a1.y = fmaf(v, m1.y, a1.y);
      a1.z = fmaf(v, m1.z, a1.z);  a1.w = fmaf(v, m1.w, a1.w);
    }
    float* slot = ws + WS_PARTIAL + ((size_t)seg * NCHUNK + c) * 2048;
    *reinterpret_cast<float4*>(slot + tid * 4)        = a0;
    *reinterpret_cast<float4*>(slot + 1024 + tid * 4) = a1;
  } else {
    // ---- light: W row dots ----
    const int wave = tid >> 6;
    const int lane = tid & 63;
    const int row  = (bid - 2 * NCHUNK) * 4 + wave;
    if (U[row] <= 0.f) return;          // stably deactivated: sV unused

    const float4* Wr = reinterpret_cast<const float4*>(W + (size_t)row * NN);
    const float4* V4 = reinterpret_cast<const float4*>(V_next);

    float acc = 0.f;
#pragma unroll
    for (int it = 0; it < 16; ++it) {
      const float4 w4 = Wr[it * 64 + lane];
      const float4 v4 = V4[it * 64 + lane];
      acc = fmaf(w4.x, v4.x, acc);
      acc = fmaf(w4.y, v4.y, acc);
      acc = fmaf(w4.z, v4.z, acc);
      acc = fmaf(w4.w, v4.w, acc);
    }
#pragma unroll
    for (int off = 32; off > 0; off >>= 1) acc += __shfl_xor(acc, off, 64);
    if (lane == 0) ws[row] = acc;
  }
}

// ---------------------------------------------------------------------------
// Stage 2: blocks 0..15 reduce partials -> pP / pPhat finals;
//          block 16 computes the unstable-rank exclusive scan.
// ---------------------------------------------------------------------------
__global__ __launch_bounds__(256)
void stage2_and_rank(const float* __restrict__ L, const float* __restrict__ U,
                     float* __restrict__ ws) {
  const int tid = threadIdx.x;

  if (blockIdx.x < 16) {
    // global col index over [0, 4096): m = t>>11 selects matrix, col = t&2047
    const int t   = blockIdx.x * 256 + tid;
    const int m   = t >> 11;
    const int col = t & 2047;
    const float* base = ws + WS_PARTIAL + (size_t)m * NCHUNK * 2048 + col;
    float s = 0.f;
#pragma unroll 8
    for (int c = 0; c < NCHUNK; ++c) s += base[(size_t)c * 2048];
    ws[8192 + m * 2048 + col] = s;
    return;
  }

  // ---- rank scan: 256 threads x 16 neurons each ----
  int* rank = reinterpret_cast<int*>(ws + 4096);
  const int base = tid * 16;
  int mflag[16];
  int cnt = 0;
#pragma unroll
  for (int j = 0; j < 16; ++j) {
    const float l = L[base + j], u = U[base + j];
    mflag[j] = (l < 0.f && u > 0.f) ? 1 : 0;
    cnt += mflag[j];
  }

  const int lane = tid & 63;
  const int wave = tid >> 6;
  int scan = cnt;
#pragma unroll
  for (int off = 1; off < 64; off <<= 1) {
    int nb = __shfl_up(scan, off, 64);
    if (lane >= off) scan += nb;
  }

  __shared__ int wave_sums[4];
  if (lane == 63) wave_sums[wave] = scan;
  __syncthreads();

  int wave_off = 0;
#pragma unroll
  for (int wv = 0; wv < 4; ++wv)
    if (wv < wave) wave_off += wave_sums[wv];

  int exc = wave_off + scan - cnt;
#pragma unroll
  for (int j = 0; j < 16; ++j) {
    rank[base + j] = exc;
    exc += mflag[j];
  }
}

// ---------------------------------------------------------------------------
// Fallback stage (used only if ws too small): R4-style atomics. Needs zeroed
// accumulators; provided by fb_zero.
// ---------------------------------------------------------------------------
__global__ __launch_bounds__(256)
void fb_zero(float* __restrict__ ws) {
  // zero pP/pPhat finals: ws[8192, 12288)
  ws[8192 + blockIdx.x * 256 + threadIdx.x] = 0.f;
}

__global__ __launch_bounds__(256)
void fb_accum(const float* __restrict__ pi, const float* __restrict__ P,
              const float* __restrict__ Phat, float* __restrict__ ws) {
  const int bid = blockIdx.x;
  const int tid = threadIdx.x;
  const int seg = bid >> 8;
  const int loc = bid & 255;
  const float* mat = seg ? Phat : P;
  float* out = ws + (seg ? 10240 : 8192);
  const int colTile = loc & 1;
  const int chunk   = loc >> 1;
  const int col  = colTile * 1024 + tid * 4;
  const int row0 = chunk * 64;

  float4 acc = make_float4(0.f, 0.f, 0.f, 0.f);
  const float* mp = mat + (size_t)row0 * NU + col;
#pragma unroll 4
  for (int r = 0; r < 64; ++r) {
    const float v = pi[row0 + r];
    const float4 m = *reinterpret_cast<const float4*>(mp);
    acc.x = fmaf(v, m.x, acc.x);
    acc.y = fmaf(v, m.y, acc.y);
    acc.z = fmaf(v, m.z, acc.z);
    acc.w = fmaf(v, m.w, acc.w);
    mp += NU;
  }
  atomicAdd(out + col + 0, acc.x);
  atomicAdd(out + col + 1, acc.y);
  atomicAdd(out + col + 2, acc.z);
  atomicAdd(out + col + 3, acc.w);
}

// ---------------------------------------------------------------------------
// Epilogue — masks + unstable formula.
// Override order: stably_deact (-C) over stably_act (sV - C).
// ---------------------------------------------------------------------------
__global__ __launch_bounds__(256)
void epilogue(const float* __restrict__ ws, const float* __restrict__ C,
              const float* __restrict__ L, const float* __restrict__ U,
              const float* __restrict__ alpha, float* __restrict__ out) {
  const int n = blockIdx.x * 256 + threadIdx.x;
  if (n >= NN) return;
  const float l = L[n], u = U[n], c = C[n];
  const int* rank = reinterpret_cast<const int*>(ws + 4096);

  float res;
  if (u <= 0.f) {
    res = -c;                       // stably deactivated
  } else if (l >= 0.f) {
    res = ws[n] - c;                // stably activated: sV - C
  } else {
    const int uu = rank[n];
    const float vhat = ws[n] - ws[10240 + uu];
    const float pos = fmaxf(vhat, 0.f);
    const float neg = fmaxf(-vhat, 0.f);
    res = pos * u / (u - l) - c - alpha[uu] * neg - ws[8192 + uu];
  }
  out[n] = res;
}

extern "C" void kernel_launch(void* const* d_in, const int* in_sizes, int n_in,
                              void* d_out, int out_size, void* d_ws, size_t ws_size,
                              hipStream_t stream) {
  const float* V_next  = (const float*)d_in[0];
  const float* W_next  = (const float*)d_in[1];
  const float* C_i     = (const float*)d_in[2];
  const float* L_i     = (const float*)d_in[3];
  const float* U_i     = (const float*)d_in[4];
  const float* P_i     = (const float*)d_in[5];
  const float* P_hat_i = (const float*)d_in[6];
  const float* pi_i    = (const float*)d_in[7];
  const float* alpha_i = (const float*)d_in[8];
  float* out = (float*)d_out;
  float* ws  = (float*)d_ws;

  if (ws_size >= WS_NEEDED) {
    // atomic-free path: heavies first, then W; stage2 reduces + ranks
    stage1<<<2 * NCHUNK + 1024, 256, 0, stream>>>(V_next, W_next, pi_i, P_i,
                                                  P_hat_i, U_i, ws);
    stage2_and_rank<<<17, 256, 0, stream>>>(L_i, U_i, ws);
  } else {
    // fallback: R4-style atomic accumulation (zero finals first, rank via stage2 block 16)
    fb_zero<<<16, 256, 0, stream>>>(ws);
    stage1<<<2 * NCHUNK + 1024, 256, 0, stream>>>(V_next, W_next, pi_i, P_i,
                                                  P_hat_i, U_i, ws);  // W rows still fine
    fb_accum<<<512, 256, 0, stream>>>(pi_i, P_i, P_hat_i, ws);
    stage2_and_rank<<<17, 256, 0, stream>>>(L_i, U_i, ws);  // blocks 0..15 overwrite finals? no:
    // NOTE: fallback unreachable when ws >= WS_NEEDED; harness ws is expected
    // to be >= 4.3 MB. If this path ever runs with tiny ws, stage2 blocks 0..15
    // would read OOB partials — guard by launching only the rank block:
  }
  epilogue<<<NN / 256, 256, 0, stream>>>(ws, C_i, L_i, U_i, alpha_i, out);
}

// Round 7
// 228.327 us; speedup vs baseline: 1.5040x; 1.0024x over previous
//
#include <hip/hip_runtime.h>

// Problem constants (match reference)
#define NN      4096   // N and N_NEXT
#define NU      2048   // NUM_UNSTABLE
#define PROWS   8192   // P_ROWS
#define NCHUNK  256    // row-chunks per P matrix (32 rows each)

// d_ws layout (floats):
//   [0,     4096)  : sV      — sV[m] = dot(V_next, W_next[m,:])
//   [4096,  8192)  : rank (int) — exclusive count of unstable with index < n
//   [8192,  10240) : pP      = pi @ P       (final)
//   [10240, 12288) : pPhat   = pi @ P_hat   (final)
//   [12288, 12288 + 2*NCHUNK*2048) : per-(matrix,rowchunk) partials (4 MB)
#define WS_PARTIAL 12288

// ---------------------------------------------------------------------------
// Stage 1: atomic-free partial mat-vec, ALL blocks uniform 64 KB of reads.
//   bid [0, 2048):      heavy: 32 rows x 512 cols of P (seg 0) / P_hat (seg 1).
//                       Thread t: rows half*16..+16, cols (t&127)*4 within the
//                       512-col slab; LDS-combine the two halves; 128 threads
//                       write the 512-float partial slice (coalesced).
//   bid [2048, 3072):   light: 4 W-rows per block, one wave per row,
//                       float4 + shfl_xor reduce; skips U<=0 rows (sV unused).
// Heavies get low bids so they dispatch first; lights backfill.
// ---------------------------------------------------------------------------
__global__ __launch_bounds__(256)
void stage1(const float* __restrict__ V_next, const float* __restrict__ W,
            const float* __restrict__ pi, const float* __restrict__ P,
            const float* __restrict__ Phat, const float* __restrict__ U,
            float* __restrict__ ws) {
  const int bid = blockIdx.x;
  const int tid = threadIdx.x;

  if (bid < 2048) {
    // ---- heavy: P / Phat partial column sums, 32 rows x 512 cols ----
    const int seg  = bid >> 10;          // 0 -> P, 1 -> Phat
    const int idx  = bid & 1023;
    const int c    = idx >> 2;           // row-chunk [0,256)
    const int cb   = idx & 3;            // col-block [0,4)
    const int row0 = c * 32;
    const int col0 = cb * 512;
    const float* mat = seg ? Phat : P;

    const int colq = tid & 127;          // col-quad within slab
    const int half = tid >> 7;           // 0: rows 0-15, 1: rows 16-31 (wave-uniform)
    const int r0   = row0 + half * 16;

    const float* mp = mat + (size_t)r0 * NU + col0 + colq * 4;
    float4 acc = make_float4(0.f, 0.f, 0.f, 0.f);
#pragma unroll
    for (int r = 0; r < 16; ++r) {
      const float v  = pi[r0 + r];       // wave-uniform scalar load
      const float4 m = *reinterpret_cast<const float4*>(mp + (size_t)r * NU);
      acc.x = fmaf(v, m.x, acc.x);
      acc.y = fmaf(v, m.y, acc.y);
      acc.z = fmaf(v, m.z, acc.z);
      acc.w = fmaf(v, m.w, acc.w);
    }

    __shared__ float4 red[128];
    if (half == 1) red[colq] = acc;
    __syncthreads();
    if (half == 0) {
      const float4 o = red[colq];
      acc.x += o.x; acc.y += o.y; acc.z += o.z; acc.w += o.w;
      float* slot = ws + WS_PARTIAL + ((size_t)seg * NCHUNK + c) * 2048 + col0;
      *reinterpret_cast<float4*>(slot + colq * 4) = acc;
    }
  } else {
    // ---- light: W row dots ----
    const int wave = tid >> 6;
    const int lane = tid & 63;
    const int row  = (bid - 2048) * 4 + wave;
    if (U[row] <= 0.f) return;           // stably deactivated: sV unused

    const float4* Wr = reinterpret_cast<const float4*>(W + (size_t)row * NN);
    const float4* V4 = reinterpret_cast<const float4*>(V_next);

    float acc = 0.f;
#pragma unroll
    for (int it = 0; it < 16; ++it) {
      const float4 w4 = Wr[it * 64 + lane];
      const float4 v4 = V4[it * 64 + lane];
      acc = fmaf(w4.x, v4.x, acc);
      acc = fmaf(w4.y, v4.y, acc);
      acc = fmaf(w4.z, v4.z, acc);
      acc = fmaf(w4.w, v4.w, acc);
    }
#pragma unroll
    for (int off = 32; off > 0; off >>= 1) acc += __shfl_xor(acc, off, 64);
    if (lane == 0) ws[row] = acc;
  }
}

// ---------------------------------------------------------------------------
// Stage 2: blocks 0..15 reduce partials -> pP / pPhat finals;
//          block 16 computes the unstable-rank exclusive scan.
// ---------------------------------------------------------------------------
__global__ __launch_bounds__(256)
void stage2_and_rank(const float* __restrict__ L, const float* __restrict__ U,
                     float* __restrict__ ws) {
  const int tid = threadIdx.x;

  if (blockIdx.x < 16) {
    const int t   = blockIdx.x * 256 + tid;
    const int m   = t >> 11;             // matrix select
    const int col = t & 2047;
    const float* base = ws + WS_PARTIAL + (size_t)m * NCHUNK * 2048 + col;
    float s = 0.f;
#pragma unroll 8
    for (int c = 0; c < NCHUNK; ++c) s += base[(size_t)c * 2048];
    ws[8192 + m * 2048 + col] = s;
    return;
  }

  // ---- rank scan: 256 threads x 16 neurons each ----
  int* rank = reinterpret_cast<int*>(ws + 4096);
  const int base = tid * 16;
  int mflag[16];
  int cnt = 0;
#pragma unroll
  for (int j = 0; j < 16; ++j) {
    const float l = L[base + j], u = U[base + j];
    mflag[j] = (l < 0.f && u > 0.f) ? 1 : 0;
    cnt += mflag[j];
  }

  const int lane = tid & 63;
  const int wave = tid >> 6;
  int scan = cnt;
#pragma unroll
  for (int off = 1; off < 64; off <<= 1) {
    int nb = __shfl_up(scan, off, 64);
    if (lane >= off) scan += nb;
  }

  __shared__ int wave_sums[4];
  if (lane == 63) wave_sums[wave] = scan;
  __syncthreads();

  int wave_off = 0;
#pragma unroll
  for (int wv = 0; wv < 4; ++wv)
    if (wv < wave) wave_off += wave_sums[wv];

  int exc = wave_off + scan - cnt;
#pragma unroll
  for (int j = 0; j < 16; ++j) {
    rank[base + j] = exc;
    exc += mflag[j];
  }
}

// ---------------------------------------------------------------------------
// Epilogue — masks + unstable formula.
// Override order: stably_deact (-C) over stably_act (sV - C).
// ---------------------------------------------------------------------------
__global__ __launch_bounds__(256)
void epilogue(const float* __restrict__ ws, const float* __restrict__ C,
              const float* __restrict__ L, const float* __restrict__ U,
              const float* __restrict__ alpha, float* __restrict__ out) {
  const int n = blockIdx.x * 256 + threadIdx.x;
  if (n >= NN) return;
  const float l = L[n], u = U[n], c = C[n];
  const int* rank = reinterpret_cast<const int*>(ws + 4096);

  float res;
  if (u <= 0.f) {
    res = -c;                       // stably deactivated
  } else if (l >= 0.f) {
    res = ws[n] - c;                // stably activated: sV - C
  } else {
    const int uu = rank[n];
    const float vhat = ws[n] - ws[10240 + uu];
    const float pos = fmaxf(vhat, 0.f);
    const float neg = fmaxf(-vhat, 0.f);
    res = pos * u / (u - l) - c - alpha[uu] * neg - ws[8192 + uu];
  }
  out[n] = res;
}

extern "C" void kernel_launch(void* const* d_in, const int* in_sizes, int n_in,
                              void* d_out, int out_size, void* d_ws, size_t ws_size,
                              hipStream_t stream) {
  const float* V_next  = (const float*)d_in[0];
  const float* W_next  = (const float*)d_in[1];
  const float* C_i     = (const float*)d_in[2];
  const float* L_i     = (const float*)d_in[3];
  const float* U_i     = (const float*)d_in[4];
  const float* P_i     = (const float*)d_in[5];
  const float* P_hat_i = (const float*)d_in[6];
  const float* pi_i    = (const float*)d_in[7];
  const float* alpha_i = (const float*)d_in[8];
  float* out = (float*)d_out;
  float* ws  = (float*)d_ws;

  stage1<<<3072, 256, 0, stream>>>(V_next, W_next, pi_i, P_i, P_hat_i, U_i, ws);
  stage2_and_rank<<<17, 256, 0, stream>>>(L_i, U_i, ws);
  epilogue<<<NN / 256, 256, 0, stream>>>(ws, C_i, L_i, U_i, alpha_i, out);
}